// Round 1
// baseline (2623.184 us; speedup 1.0000x reference)
//
#include <hip/hip_runtime.h>
#include <hip/hip_bf16.h>

// Problem dims
#define LL 12
#define BB 32
#define SS 197
#define DV 768
#define DD 512
#define CC 48
#define VV 49
#define LOSS_DEN 786432.0f  // 32*48*512

// ---------------------------------------------------------------------------
// Pool: X[l,b,0,:] = feats[l,b,0,:]; X[l,b,1+i,:] = mean(feats[l,b,1+s..e,:])
// grid = L*B*V blocks, 256 threads
__global__ __launch_bounds__(256) void pool_kernel(const float* __restrict__ feats,
                                                   float* __restrict__ X) {
    int row = blockIdx.x;
    int t = threadIdx.x;
    int v = row % VV;
    int lb = row / VV;
    const float* f = feats + (size_t)lb * SS * DV;
    float* xr = X + (size_t)row * DV;
    if (v == 0) {
        for (int d = t; d < DV; d += 256) xr[d] = f[d];
    } else {
        int i = v - 1;
        int s = (i * 196) / 48;
        int e = ((i + 1) * 196 + 47) / 48;
        float inv = 1.0f / (float)(e - s);
        for (int d = t; d < DV; d += 256) {
            float acc = 0.0f;
            for (int j = s; j < e; ++j) acc += f[(size_t)(1 + j) * DV + d];
            xr[d] = acc * inv;
        }
    }
}

// ---------------------------------------------------------------------------
// Generic f32 GEMM: C[m,n] = sum_k A[m,k]*W[n,k] + bias[n]
// A row-major with row stride lda; W row-major (N x K); C row stride 512.
// Tiles: 64x64, K-tile 32. 256 threads, 4x4 per thread. M,K multiples of 64/32.
__global__ __launch_bounds__(256) void gemm_nt(const float* __restrict__ A, int lda,
                                               const float* __restrict__ W, int K,
                                               const float* __restrict__ bias,
                                               float* __restrict__ Cout) {
    __shared__ float As[32][65];
    __shared__ float Bs[32][65];
    int t = threadIdx.x;
    int m0 = blockIdx.x * 64;
    int n0 = blockIdx.y * 64;
    int r = t >> 2;
    int kc = (t & 3) * 8;
    int tx = t & 15, ty = t >> 4;
    float acc[4][4] = {};
    for (int k0 = 0; k0 < K; k0 += 32) {
        const float4* pa = (const float4*)(A + (size_t)(m0 + r) * lda + k0 + kc);
        float4 a0 = pa[0], a1 = pa[1];
        const float4* pw = (const float4*)(W + (size_t)(n0 + r) * K + k0 + kc);
        float4 w0 = pw[0], w1 = pw[1];
        As[kc + 0][r] = a0.x; As[kc + 1][r] = a0.y; As[kc + 2][r] = a0.z; As[kc + 3][r] = a0.w;
        As[kc + 4][r] = a1.x; As[kc + 5][r] = a1.y; As[kc + 6][r] = a1.z; As[kc + 7][r] = a1.w;
        Bs[kc + 0][r] = w0.x; Bs[kc + 1][r] = w0.y; Bs[kc + 2][r] = w0.z; Bs[kc + 3][r] = w0.w;
        Bs[kc + 4][r] = w1.x; Bs[kc + 5][r] = w1.y; Bs[kc + 6][r] = w1.z; Bs[kc + 7][r] = w1.w;
        __syncthreads();
#pragma unroll
        for (int kk = 0; kk < 32; ++kk) {
            float a[4], b[4];
#pragma unroll
            for (int i = 0; i < 4; ++i) { a[i] = As[kk][ty * 4 + i]; b[i] = Bs[kk][tx * 4 + i]; }
#pragma unroll
            for (int i = 0; i < 4; ++i)
#pragma unroll
                for (int j = 0; j < 4; ++j) acc[i][j] += a[i] * b[j];
        }
        __syncthreads();
    }
#pragma unroll
    for (int i = 0; i < 4; ++i) {
        int m = m0 + ty * 4 + i;
#pragma unroll
        for (int j = 0; j < 4; ++j) {
            int n = n0 + tx * 4 + j;
            float v = acc[i][j] + (bias ? bias[n] : 0.0f);
            Cout[(size_t)m * DD + n] = v;
        }
    }
}

// ---------------------------------------------------------------------------
// Attention + fuse, one wave per (b, concept). Online softmax, single pass.
__global__ __launch_bounds__(64) void attn_fuse(const float* __restrict__ q,
                                                const float* __restrict__ vt_l,
                                                const float* __restrict__ fuse_prev,
                                                float* __restrict__ fuse_out,
                                                float* __restrict__ loss_acc, int do_loss) {
    int bc = blockIdx.x;
    int lane = threadIdx.x;
    int b = bc / CC;
    const float* qrow = q + (size_t)bc * DD + lane * 8;
    float4 q0 = *(const float4*)qrow;
    float4 q1 = *(const float4*)(qrow + 4);
    float ql[8] = {q0.x, q0.y, q0.z, q0.w, q1.x, q1.y, q1.z, q1.w};
    const float* vtb = vt_l + (size_t)b * VV * DD + lane * 8;
    float m = -1e30f, s = 0.0f;
    float acc[8] = {};
    for (int v = 0; v < VV; ++v) {
        const float* rp = vtb + v * DD;
        float4 r0 = *(const float4*)rp;
        float4 r1 = *(const float4*)(rp + 4);
        float rv[8] = {r0.x, r0.y, r0.z, r0.w, r1.x, r1.y, r1.z, r1.w};
        float p = 0.0f;
#pragma unroll
        for (int j = 0; j < 8; ++j) p += ql[j] * rv[j];
#pragma unroll
        for (int off = 32; off > 0; off >>= 1) p += __shfl_xor(p, off);
        float nm = fmaxf(m, p);
        float sc = __expf(m - nm);
        float w = __expf(p - nm);
        s = s * sc + w;
#pragma unroll
        for (int j = 0; j < 8; ++j) acc[j] = acc[j] * sc + w * rv[j];
        m = nm;
    }
    float inv = 1.0f / s;
    float f[8];
#pragma unroll
    for (int j = 0; j < 8; ++j) f[j] = acc[j] * inv;
    float* fo = fuse_out + (size_t)bc * DD + lane * 8;
    float4 o0 = {f[0], f[1], f[2], f[3]};
    float4 o1 = {f[4], f[5], f[6], f[7]};
    *(float4*)fo = o0;
    *(float4*)(fo + 4) = o1;
    if (do_loss) {
        const float* fp = fuse_prev + (size_t)bc * DD + lane * 8;
        float4 p0 = *(const float4*)fp;
        float4 p1 = *(const float4*)(fp + 4);
        float pv[8] = {p0.x, p0.y, p0.z, p0.w, p1.x, p1.y, p1.z, p1.w};
        float d2 = 0.0f;
#pragma unroll
        for (int j = 0; j < 8; ++j) { float dd = f[j] - pv[j]; d2 += dd * dd; }
#pragma unroll
        for (int off = 32; off > 0; off >>= 1) d2 += __shfl_xor(d2, off);
        if (lane == 0) atomicAdd(loss_acc, d2);
    }
}

// ---------------------------------------------------------------------------
// gate/upd GEMMs fused: A = [fuse | q | ctx] (virtual 1536x1536).
// gate = sigmoid(A @ Wg^T + bg)   (K=1536)
// upd  = tanh(A[:, :1024] @ Wu^T + bu)  (K=1024)
// qout = gate*q + (1-gate)*upd
__global__ __launch_bounds__(256) void gate_upd(const float* __restrict__ fuse,
                                                const float* __restrict__ qin,
                                                const float* __restrict__ ctx_l,
                                                const float* __restrict__ Wg,
                                                const float* __restrict__ bg,
                                                const float* __restrict__ Wu,
                                                const float* __restrict__ bu,
                                                float* __restrict__ qout) {
    __shared__ float As[32][65];
    __shared__ float Gs[32][65];
    __shared__ float Us[32][65];
    int t = threadIdx.x;
    int m0 = blockIdx.x * 64;
    int n0 = blockIdx.y * 64;
    int r = t >> 2;
    int kc = (t & 3) * 8;
    int tx = t & 15, ty = t >> 4;
    float ag[4][4] = {};
    float au[4][4] = {};
    int mrow = m0 + r;
    int brow = mrow / CC;
    int nrow = n0 + r;
    for (int k0 = 0; k0 < 1536; k0 += 32) {
        int k = k0 + kc;
        const float* src;
        if (k < 512) src = fuse + (size_t)mrow * DD + k;
        else if (k < 1024) src = qin + (size_t)mrow * DD + (k - 512);
        else src = ctx_l + (size_t)brow * DD + (k - 1024);
        float4 a0 = *(const float4*)src;
        float4 a1 = *(const float4*)(src + 4);
        const float4* pg = (const float4*)(Wg + (size_t)nrow * 1536 + k);
        float4 g0 = pg[0], g1 = pg[1];
        As[kc + 0][r] = a0.x; As[kc + 1][r] = a0.y; As[kc + 2][r] = a0.z; As[kc + 3][r] = a0.w;
        As[kc + 4][r] = a1.x; As[kc + 5][r] = a1.y; As[kc + 6][r] = a1.z; As[kc + 7][r] = a1.w;
        Gs[kc + 0][r] = g0.x; Gs[kc + 1][r] = g0.y; Gs[kc + 2][r] = g0.z; Gs[kc + 3][r] = g0.w;
        Gs[kc + 4][r] = g1.x; Gs[kc + 5][r] = g1.y; Gs[kc + 6][r] = g1.z; Gs[kc + 7][r] = g1.w;
        if (k0 < 1024) {
            const float4* pu = (const float4*)(Wu + (size_t)nrow * 1024 + k);
            float4 u0 = pu[0], u1 = pu[1];
            Us[kc + 0][r] = u0.x; Us[kc + 1][r] = u0.y; Us[kc + 2][r] = u0.z; Us[kc + 3][r] = u0.w;
            Us[kc + 4][r] = u1.x; Us[kc + 5][r] = u1.y; Us[kc + 6][r] = u1.z; Us[kc + 7][r] = u1.w;
        }
        __syncthreads();
        if (k0 < 1024) {
#pragma unroll
            for (int kk = 0; kk < 32; ++kk) {
                float a[4], g[4], u[4];
#pragma unroll
                for (int i = 0; i < 4; ++i) {
                    a[i] = As[kk][ty * 4 + i];
                    g[i] = Gs[kk][tx * 4 + i];
                    u[i] = Us[kk][tx * 4 + i];
                }
#pragma unroll
                for (int i = 0; i < 4; ++i)
#pragma unroll
                    for (int j = 0; j < 4; ++j) {
                        ag[i][j] += a[i] * g[j];
                        au[i][j] += a[i] * u[j];
                    }
            }
        } else {
#pragma unroll
            for (int kk = 0; kk < 32; ++kk) {
                float a[4], g[4];
#pragma unroll
                for (int i = 0; i < 4; ++i) {
                    a[i] = As[kk][ty * 4 + i];
                    g[i] = Gs[kk][tx * 4 + i];
                }
#pragma unroll
                for (int i = 0; i < 4; ++i)
#pragma unroll
                    for (int j = 0; j < 4; ++j) ag[i][j] += a[i] * g[j];
            }
        }
        __syncthreads();
    }
#pragma unroll
    for (int i = 0; i < 4; ++i) {
        int m = m0 + ty * 4 + i;
#pragma unroll
        for (int j = 0; j < 4; ++j) {
            int n = n0 + tx * 4 + j;
            float g = 1.0f / (1.0f + __expf(-(ag[i][j] + bg[n])));
            float u = tanhf(au[i][j] + bu[n]);
            float qv = qin[(size_t)m * DD + n];
            qout[(size_t)m * DD + n] = g * qv + (1.0f - g) * u;
        }
    }
}

// ---------------------------------------------------------------------------
__global__ __launch_bounds__(256) void init_q_kernel(const float* __restrict__ ce,
                                                     float* __restrict__ q0) {
    int i = blockIdx.x * 256 + threadIdx.x;  // total B*C*D = 786432 exactly
    q0[i] = ce[i % (CC * DD)];
}

__global__ void zero1_kernel(float* p) { p[0] = 0.0f; }

// ---------------------------------------------------------------------------
// Final: normalize last fuse rows, image_logits, cls_logits, loss.
__global__ __launch_bounds__(256) void final_kernel(const float* __restrict__ fuse_last,
                                                    const float* __restrict__ ce,
                                                    const float* __restrict__ W_cls,
                                                    const float* __restrict__ b_cls,
                                                    const float* __restrict__ loss_acc,
                                                    float* __restrict__ out) {
    int b = blockIdx.x;
    int t = threadIdx.x;
    int w = t >> 6, lane = t & 63;
    __shared__ float invn[CC];
    __shared__ float img[CC];
    const float* fb = fuse_last + (size_t)b * CC * DD;
    for (int c = w; c < CC; c += 4) {
        const float* fr = fb + (size_t)c * DD + lane * 8;
        float4 a0 = *(const float4*)fr;
        float4 a1 = *(const float4*)(fr + 4);
        float ss = a0.x * a0.x + a0.y * a0.y + a0.z * a0.z + a0.w * a0.w +
                   a1.x * a1.x + a1.y * a1.y + a1.z * a1.z + a1.w * a1.w;
#pragma unroll
        for (int off = 32; off > 0; off >>= 1) ss += __shfl_xor(ss, off);
        if (lane == 0) invn[c] = 1.0f / fmaxf(sqrtf(ss), 1e-12f);
    }
    __syncthreads();
    for (int g = w; g < CC; g += 4) {
        int k = g / 6;
        const float* ar = ce + (size_t)g * DD + lane * 8;
        float4 c0 = *(const float4*)ar;
        float4 c1 = *(const float4*)(ar + 4);
        float av[8] = {c0.x, c0.y, c0.z, c0.w, c1.x, c1.y, c1.z, c1.w};
        float accp = 0.0f;
        for (int p = 0; p < 6; ++p) {
            int row = k * 6 + p;
            const float* fr = fb + (size_t)row * DD + lane * 8;
            float4 f0 = *(const float4*)fr;
            float4 f1 = *(const float4*)(fr + 4);
            float fv[8] = {f0.x, f0.y, f0.z, f0.w, f1.x, f1.y, f1.z, f1.w};
            float d = 0.0f;
#pragma unroll
            for (int j = 0; j < 8; ++j) d += fv[j] * av[j];
            accp += d * invn[row];
        }
#pragma unroll
        for (int off = 32; off > 0; off >>= 1) accp += __shfl_xor(accp, off);
        if (lane == 0) img[g] = accp * (100.0f / 6.0f);
    }
    __syncthreads();
    if (t < CC) out[BB * 7 + b * CC + t] = img[t];
    if (t < 7) {
        float sacc = b_cls[t];
        for (int c = 0; c < CC; ++c) sacc += img[c] * W_cls[t * CC + c];
        out[b * 7 + t] = sacc;
    }
    if (b == 0 && t == 0) out[BB * 7 + BB * CC] = loss_acc[0] * (1.0f / LOSS_DEN);
}

// ---------------------------------------------------------------------------
extern "C" void kernel_launch(void* const* d_in, const int* in_sizes, int n_in,
                              void* d_out, int out_size, void* d_ws, size_t ws_size,
                              hipStream_t stream) {
    const float* feats = (const float*)d_in[0];
    const float* ce = (const float*)d_in[1];
    const float* W_lin = (const float*)d_in[2];
    const float* b_lin = (const float*)d_in[3];
    const float* W_proj = (const float*)d_in[4];
    const float* W_gate = (const float*)d_in[5];
    const float* b_gate = (const float*)d_in[6];
    const float* W_upd = (const float*)d_in[7];
    const float* b_upd = (const float*)d_in[8];
    const float* W_cls = (const float*)d_in[9];
    const float* b_cls = (const float*)d_in[10];
    float* out = (float*)d_out;

    float* ws = (float*)d_ws;
    size_t offX = 0;
    size_t offVt = offX + (size_t)LL * BB * VV * DV;    // 14,450,688
    size_t offCtx = offVt + (size_t)LL * BB * VV * DD;  // +9,633,792
    size_t offQ0 = offCtx + (size_t)LL * BB * DD;       // +196,608
    size_t offQ1 = offQ0 + (size_t)BB * CC * DD;        // +786,432
    size_t offF0 = offQ1 + (size_t)BB * CC * DD;
    size_t offF1 = offF0 + (size_t)BB * CC * DD;
    size_t offLoss = offF1 + (size_t)BB * CC * DD;
    float* X = ws + offX;
    float* vt = ws + offVt;
    float* ctx = ws + offCtx;
    float* qbuf[2] = {ws + offQ0, ws + offQ1};
    float* fbuf[2] = {ws + offF0, ws + offF1};
    float* loss = ws + offLoss;

    // Precompute (layer-independent)
    pool_kernel<<<LL * BB * VV, 256, 0, stream>>>(feats, X);
    {
        dim3 g(LL * BB * VV / 64, DD / 64);
        gemm_nt<<<g, 256, 0, stream>>>(X, DV, W_lin, DV, b_lin, vt);
    }
    {
        dim3 g(LL * BB / 64, DD / 64);
        gemm_nt<<<g, 256, 0, stream>>>(feats, SS * DV, W_proj, DV, nullptr, ctx);
    }
    init_q_kernel<<<(BB * CC * DD) / 256, 256, 0, stream>>>(ce, qbuf[0]);
    zero1_kernel<<<1, 1, 0, stream>>>(loss);

    int qc = 0;
    for (int l = 0; l < LL; ++l) {
        float* fcur = fbuf[l & 1];
        float* fprev = fbuf[(l & 1) ^ 1];
        attn_fuse<<<BB * CC, 64, 0, stream>>>(qbuf[qc], vt + (size_t)l * BB * VV * DD, fprev,
                                              fcur, loss, l > 0 ? 1 : 0);
        if (l < LL - 1) {
            dim3 g((BB * CC) / 64, DD / 64);
            gate_upd<<<g, 256, 0, stream>>>(fcur, qbuf[qc], ctx + (size_t)l * BB * DD, W_gate,
                                            b_gate, W_upd, b_upd, qbuf[qc ^ 1]);
            qc ^= 1;
        }
    }

    final_kernel<<<BB, 256, 0, stream>>>(fbuf[(LL - 1) & 1], ce, W_cls, b_cls, loss, out);
}

// Round 2
// 1195.019 us; speedup vs baseline: 2.1951x; 2.1951x over previous
//
#include <hip/hip_runtime.h>
#include <hip/hip_bf16.h>

#define LL 12
#define BB 32
#define SS 197
#define DV 768
#define DD 512
#define CC 48
#define VV 49
#define LOSS_DEN 786432.0f

typedef unsigned short u16;
typedef unsigned int u32;
using bf16x8 = __attribute__((ext_vector_type(8))) __bf16;
using f32x4 = __attribute__((ext_vector_type(4))) float;

__device__ __forceinline__ u16 bf16h(float x) {
    u32 u = __builtin_bit_cast(u32, x);
    return (u16)((u + 0x7FFFu + ((u >> 16) & 1u)) >> 16);
}
__device__ __forceinline__ float bf2f(u16 h) {
    u32 u = ((u32)h) << 16;
    return __builtin_bit_cast(float, u);
}
__device__ __forceinline__ f32x4 mfma16(bf16x8 a, bf16x8 b, f32x4 c) {
    return __builtin_amdgcn_mfma_f32_16x16x32_bf16(a, b, c, 0, 0, 0);
}
__device__ __forceinline__ void gl_lds16(const void* g, void* s) {
    __builtin_amdgcn_global_load_lds((const __attribute__((address_space(1))) u32*)g,
                                     (__attribute__((address_space(3))) u32*)s, 16, 0, 0);
}

// ---------------------------------------------------------------------------
// Pool + bf16 hi/lo split of X (adaptive avg pool of feats)
__global__ __launch_bounds__(256) void pool_split(const float* __restrict__ feats,
                                                  u16* __restrict__ Xh, u16* __restrict__ Xl) {
    int row = blockIdx.x;
    int t = threadIdx.x;
    int v = row % VV;
    int lb = row / VV;
    const float* f = feats + (size_t)lb * SS * DV;
    for (int d = t; d < DV; d += 256) {
        float val;
        if (v == 0) {
            val = f[d];
        } else {
            int i = v - 1;
            int s = (i * 196) / 48;
            int e = ((i + 1) * 196 + 47) / 48;
            float acc = 0.0f;
            for (int j = s; j < e; ++j) acc += f[(size_t)(1 + j) * DV + d];
            val = acc / (float)(e - s);
        }
        u16 h = bf16h(val);
        Xh[(size_t)row * DV + d] = h;
        Xl[(size_t)row * DV + d] = bf16h(val - bf2f(h));
    }
}

// Generic f32 -> (hi,lo) bf16 planes
__global__ __launch_bounds__(256) void split_kernel(const float* __restrict__ in,
                                                    u16* __restrict__ h, u16* __restrict__ l, int n) {
    int i = blockIdx.x * 256 + threadIdx.x;
    if (i < n) {
        float v = in[i];
        u16 hh = bf16h(v);
        h[i] = hh;
        l[i] = bf16h(v - bf2f(hh));
    }
}

// ---------------------------------------------------------------------------
// f32 GEMM kept only for small ctx projection: C[m,n] = sum_k A[m,k]*W[n,k]
__global__ __launch_bounds__(256) void gemm_nt(const float* __restrict__ A, int lda,
                                               const float* __restrict__ W, int K,
                                               const float* __restrict__ bias,
                                               float* __restrict__ Cout) {
    __shared__ float As[32][65];
    __shared__ float Bs[32][65];
    int t = threadIdx.x;
    int m0 = blockIdx.x * 64;
    int n0 = blockIdx.y * 64;
    int r = t >> 2;
    int kc = (t & 3) * 8;
    int tx = t & 15, ty = t >> 4;
    float acc[4][4] = {};
    for (int k0 = 0; k0 < K; k0 += 32) {
        const float4* pa = (const float4*)(A + (size_t)(m0 + r) * lda + k0 + kc);
        float4 a0 = pa[0], a1 = pa[1];
        const float4* pw = (const float4*)(W + (size_t)(n0 + r) * K + k0 + kc);
        float4 w0 = pw[0], w1 = pw[1];
        As[kc + 0][r] = a0.x; As[kc + 1][r] = a0.y; As[kc + 2][r] = a0.z; As[kc + 3][r] = a0.w;
        As[kc + 4][r] = a1.x; As[kc + 5][r] = a1.y; As[kc + 6][r] = a1.z; As[kc + 7][r] = a1.w;
        Bs[kc + 0][r] = w0.x; Bs[kc + 1][r] = w0.y; Bs[kc + 2][r] = w0.z; Bs[kc + 3][r] = w0.w;
        Bs[kc + 4][r] = w1.x; Bs[kc + 5][r] = w1.y; Bs[kc + 6][r] = w1.z; Bs[kc + 7][r] = w1.w;
        __syncthreads();
#pragma unroll
        for (int kk = 0; kk < 32; ++kk) {
            float a[4], b[4];
#pragma unroll
            for (int i = 0; i < 4; ++i) { a[i] = As[kk][ty * 4 + i]; b[i] = Bs[kk][tx * 4 + i]; }
#pragma unroll
            for (int i = 0; i < 4; ++i)
#pragma unroll
                for (int j = 0; j < 4; ++j) acc[i][j] += a[i] * b[j];
        }
        __syncthreads();
    }
#pragma unroll
    for (int i = 0; i < 4; ++i) {
        int m = m0 + ty * 4 + i;
#pragma unroll
        for (int j = 0; j < 4; ++j) {
            int n = n0 + tx * 4 + j;
            Cout[(size_t)m * DD + n] = acc[i][j] + (bias ? bias[n] : 0.0f);
        }
    }
}

// ---------------------------------------------------------------------------
// vt = X @ W_lin.T + b_lin  via bf16x3 MFMA.  BM=128, BN=64, BK=32, 4 waves.
// LDS layout (u16 units, per 12288-u16 buffer): Ah 0, Al 4096, Bh 8192, Bl 10240.
// Swizzle: stored 16B-slot = logical-slot ^ ((row>>1)&3)  (2-way banks => free).
__global__ __launch_bounds__(256, 2) void vt_gemm(const u16* __restrict__ Xh, const u16* __restrict__ Xl,
                                                  const u16* __restrict__ Wh, const u16* __restrict__ Wl,
                                                  const float* __restrict__ bias, float* __restrict__ C) {
    __shared__ u16 sm[24576];
    int tid = threadIdx.x;
    int w = tid >> 6, l = tid & 63, lr = l & 15, ls = l >> 4;
    int m0 = blockIdx.x * 128, n0 = blockIdx.y * 64;
    f32x4 acc[2][4];
#pragma unroll
    for (int i = 0; i < 2; ++i)
#pragma unroll
        for (int j = 0; j < 4; ++j) acc[i][j] = f32x4{0.f, 0.f, 0.f, 0.f};

    auto stage = [&](u16* dst, int k0) {
#pragma unroll
        for (int is = 0; is < 6; ++is) {
            int q = is * 256 + tid;
            const u16* src;
            int off;
            if (is < 2)      { int qr = q;        int row = qr >> 2, sl = qr & 3; src = Xh + (size_t)(m0 + row) * DV + k0 + ((sl ^ ((row >> 1) & 3)) << 3); off = qr * 8; }
            else if (is < 4) { int qr = q - 512;  int row = qr >> 2, sl = qr & 3; src = Xl + (size_t)(m0 + row) * DV + k0 + ((sl ^ ((row >> 1) & 3)) << 3); off = 4096 + qr * 8; }
            else if (is < 5) { int qr = q - 1024; int row = qr >> 2, sl = qr & 3; src = Wh + (size_t)(n0 + row) * DV + k0 + ((sl ^ ((row >> 1) & 3)) << 3); off = 8192 + qr * 8; }
            else             { int qr = q - 1280; int row = qr >> 2, sl = qr & 3; src = Wl + (size_t)(n0 + row) * DV + k0 + ((sl ^ ((row >> 1) & 3)) << 3); off = 10240 + qr * 8; }
            gl_lds16(src, dst + off);
        }
    };

    stage(sm, 0);
    __syncthreads();
    for (int t = 0; t < 24; ++t) {
        u16* cur = sm + ((t & 1) ? 12288 : 0);
        u16* nxt = sm + ((t & 1) ? 0 : 12288);
        if (t + 1 < 24) stage(nxt, (t + 1) * 32);
        bf16x8 ah[2], al2[2], bh[4], bl2[4];
#pragma unroll
        for (int rf = 0; rf < 2; ++rf) {
            int row = 32 * w + 16 * rf + lr;
            int ro = row * 32 + ((ls ^ ((row >> 1) & 3)) << 3);
            ah[rf] = *(const bf16x8*)(cur + ro);
            al2[rf] = *(const bf16x8*)(cur + 4096 + ro);
        }
#pragma unroll
        for (int cf = 0; cf < 4; ++cf) {
            int n = 16 * cf + lr;
            int no = n * 32 + ((ls ^ ((n >> 1) & 3)) << 3);
            bh[cf] = *(const bf16x8*)(cur + 8192 + no);
            bl2[cf] = *(const bf16x8*)(cur + 10240 + no);
        }
#pragma unroll
        for (int rf = 0; rf < 2; ++rf)
#pragma unroll
            for (int cf = 0; cf < 4; ++cf) {
                acc[rf][cf] = mfma16(ah[rf], bh[cf], acc[rf][cf]);
                acc[rf][cf] = mfma16(ah[rf], bl2[cf], acc[rf][cf]);
                acc[rf][cf] = mfma16(al2[rf], bh[cf], acc[rf][cf]);
            }
        __syncthreads();
    }
#pragma unroll
    for (int rf = 0; rf < 2; ++rf)
#pragma unroll
        for (int cf = 0; cf < 4; ++cf)
#pragma unroll
            for (int r = 0; r < 4; ++r) {
                int row = m0 + 32 * w + 16 * rf + 4 * ls + r;
                int col = n0 + 16 * cf + lr;
                C[(size_t)row * DD + col] = acc[rf][cf][r] + bias[col];
            }
}

// ---------------------------------------------------------------------------
// gate/upd fused bf16x3 MFMA.  A = [fuse | q | ctx] gathered; BM=64, BN=64, BK=32.
// LDS per 12288-u16 buffer: Ah 0, Al 2048, Gh 4096, Gl 6144, Uh 8192, Ul 10240.
__global__ __launch_bounds__(256, 2) void gate_upd_mfma(
    const u16* __restrict__ fhp, const u16* __restrict__ flp,
    const u16* __restrict__ qhp, const u16* __restrict__ qlp,
    const u16* __restrict__ chp, const u16* __restrict__ clp,
    const u16* __restrict__ Wgh, const u16* __restrict__ Wgl,
    const u16* __restrict__ Wuh, const u16* __restrict__ Wul,
    const float* __restrict__ bg, const float* __restrict__ bu,
    const float* __restrict__ qin, float* __restrict__ qout,
    u16* __restrict__ qoh, u16* __restrict__ qol) {
    __shared__ u16 sm[24576];
    int tid = threadIdx.x;
    int w = tid >> 6, l = tid & 63, lr = l & 15, ls = l >> 4;
    int m0 = blockIdx.x * 64, n0 = blockIdx.y * 64;
    f32x4 ag[4], au[4];
#pragma unroll
    for (int j = 0; j < 4; ++j) { ag[j] = f32x4{0.f, 0.f, 0.f, 0.f}; au[j] = f32x4{0.f, 0.f, 0.f, 0.f}; }

    auto stage = [&](u16* dst, int k0) {
        int q = tid, row = q >> 2, sl = q & 3;
        int kk = ((sl ^ ((row >> 1) & 3)) << 3);
        int mrow = m0 + row, nrow = n0 + row;
        const u16 *sa, *sb;
        if (k0 < 512)       { sa = fhp + (size_t)mrow * DD + k0 + kk;          sb = flp + (size_t)mrow * DD + k0 + kk; }
        else if (k0 < 1024) { sa = qhp + (size_t)mrow * DD + (k0 - 512) + kk;  sb = qlp + (size_t)mrow * DD + (k0 - 512) + kk; }
        else { int brow = mrow / CC; sa = chp + (size_t)brow * DD + (k0 - 1024) + kk; sb = clp + (size_t)brow * DD + (k0 - 1024) + kk; }
        gl_lds16(sa, dst + q * 8);
        gl_lds16(sb, dst + 2048 + q * 8);
        gl_lds16(Wgh + (size_t)nrow * 1536 + k0 + kk, dst + 4096 + q * 8);
        gl_lds16(Wgl + (size_t)nrow * 1536 + k0 + kk, dst + 6144 + q * 8);
        if (k0 < 1024) {
            gl_lds16(Wuh + (size_t)nrow * 1024 + k0 + kk, dst + 8192 + q * 8);
            gl_lds16(Wul + (size_t)nrow * 1024 + k0 + kk, dst + 10240 + q * 8);
        }
    };

    stage(sm, 0);
    __syncthreads();
    for (int t = 0; t < 48; ++t) {
        u16* cur = sm + ((t & 1) ? 12288 : 0);
        u16* nxt = sm + ((t & 1) ? 0 : 12288);
        if (t + 1 < 48) stage(nxt, (t + 1) * 32);
        int arow = 16 * w + lr;
        int ao = arow * 32 + ((ls ^ ((arow >> 1) & 3)) << 3);
        bf16x8 a_h = *(const bf16x8*)(cur + ao);
        bf16x8 a_l = *(const bf16x8*)(cur + 2048 + ao);
#pragma unroll
        for (int cf = 0; cf < 4; ++cf) {
            int n = 16 * cf + lr;
            int no = n * 32 + ((ls ^ ((n >> 1) & 3)) << 3);
            bf16x8 g_h = *(const bf16x8*)(cur + 4096 + no);
            bf16x8 g_l = *(const bf16x8*)(cur + 6144 + no);
            ag[cf] = mfma16(a_h, g_h, ag[cf]);
            ag[cf] = mfma16(a_h, g_l, ag[cf]);
            ag[cf] = mfma16(a_l, g_h, ag[cf]);
            if (t < 32) {
                bf16x8 u_h = *(const bf16x8*)(cur + 8192 + no);
                bf16x8 u_l = *(const bf16x8*)(cur + 10240 + no);
                au[cf] = mfma16(a_h, u_h, au[cf]);
                au[cf] = mfma16(a_h, u_l, au[cf]);
                au[cf] = mfma16(a_l, u_h, au[cf]);
            }
        }
        __syncthreads();
    }
#pragma unroll
    for (int cf = 0; cf < 4; ++cf)
#pragma unroll
        for (int r = 0; r < 4; ++r) {
            int row = m0 + 16 * w + 4 * ls + r;
            int col = n0 + 16 * cf + lr;
            float g = 1.0f / (1.0f + __expf(-(ag[cf][r] + bg[col])));
            float u = tanhf(au[cf][r] + bu[col]);
            size_t o = (size_t)row * DD + col;
            float qv = qin[o];
            float qo = g * qv + (1.0f - g) * u;
            qout[o] = qo;
            u16 hh = bf16h(qo);
            qoh[o] = hh;
            qol[o] = bf16h(qo - bf2f(hh));
        }
}

// ---------------------------------------------------------------------------
// Attention + fuse (f32), one wave per (b, concept); also emits fuse hi/lo planes.
__global__ __launch_bounds__(64) void attn_fuse(const float* __restrict__ q,
                                                const float* __restrict__ vt_l,
                                                const float* __restrict__ fuse_prev,
                                                float* __restrict__ fuse_out,
                                                u16* __restrict__ fhp, u16* __restrict__ flp,
                                                float* __restrict__ loss_acc, int do_loss) {
    int bc = blockIdx.x;
    int lane = threadIdx.x;
    int b = bc / CC;
    const float* qrow = q + (size_t)bc * DD + lane * 8;
    float4 q0 = *(const float4*)qrow;
    float4 q1 = *(const float4*)(qrow + 4);
    float ql[8] = {q0.x, q0.y, q0.z, q0.w, q1.x, q1.y, q1.z, q1.w};
    const float* vtb = vt_l + (size_t)b * VV * DD + lane * 8;
    float m = -1e30f, s = 0.0f;
    float acc[8] = {};
    for (int v = 0; v < VV; ++v) {
        const float* rp = vtb + v * DD;
        float4 r0 = *(const float4*)rp;
        float4 r1 = *(const float4*)(rp + 4);
        float rv[8] = {r0.x, r0.y, r0.z, r0.w, r1.x, r1.y, r1.z, r1.w};
        float p = 0.0f;
#pragma unroll
        for (int j = 0; j < 8; ++j) p += ql[j] * rv[j];
#pragma unroll
        for (int off = 32; off > 0; off >>= 1) p += __shfl_xor(p, off);
        float nm = fmaxf(m, p);
        float sc = __expf(m - nm);
        float wgt = __expf(p - nm);
        s = s * sc + wgt;
#pragma unroll
        for (int j = 0; j < 8; ++j) acc[j] = acc[j] * sc + wgt * rv[j];
        m = nm;
    }
    float inv = 1.0f / s;
    float f[8];
#pragma unroll
    for (int j = 0; j < 8; ++j) f[j] = acc[j] * inv;
    size_t ob = (size_t)bc * DD + lane * 8;
    float* fo = fuse_out + ob;
    *(float4*)fo = float4{f[0], f[1], f[2], f[3]};
    *(float4*)(fo + 4) = float4{f[4], f[5], f[6], f[7]};
#pragma unroll
    for (int j = 0; j < 8; ++j) {
        u16 hh = bf16h(f[j]);
        fhp[ob + j] = hh;
        flp[ob + j] = bf16h(f[j] - bf2f(hh));
    }
    if (do_loss) {
        const float* fp = fuse_prev + ob;
        float4 p0 = *(const float4*)fp;
        float4 p1 = *(const float4*)(fp + 4);
        float pv[8] = {p0.x, p0.y, p0.z, p0.w, p1.x, p1.y, p1.z, p1.w};
        float d2 = 0.0f;
#pragma unroll
        for (int j = 0; j < 8; ++j) { float dd = f[j] - pv[j]; d2 += dd * dd; }
#pragma unroll
        for (int off = 32; off > 0; off >>= 1) d2 += __shfl_xor(d2, off);
        if (lane == 0) atomicAdd(loss_acc, d2);
    }
}

// ---------------------------------------------------------------------------
__global__ __launch_bounds__(256) void init_q_kernel(const float* __restrict__ ce,
                                                     float* __restrict__ q0,
                                                     u16* __restrict__ qh, u16* __restrict__ ql) {
    int i = blockIdx.x * 256 + threadIdx.x;  // B*C*D = 786432 exactly
    float v = ce[i % (CC * DD)];
    q0[i] = v;
    u16 hh = bf16h(v);
    qh[i] = hh;
    ql[i] = bf16h(v - bf2f(hh));
}

__global__ void zero1_kernel(float* p) { p[0] = 0.0f; }

// ---------------------------------------------------------------------------
__global__ __launch_bounds__(256) void final_kernel(const float* __restrict__ fuse_last,
                                                    const float* __restrict__ ce,
                                                    const float* __restrict__ W_cls,
                                                    const float* __restrict__ b_cls,
                                                    const float* __restrict__ loss_acc,
                                                    float* __restrict__ out) {
    int b = blockIdx.x;
    int t = threadIdx.x;
    int w = t >> 6, lane = t & 63;
    __shared__ float invn[CC];
    __shared__ float img[CC];
    const float* fb = fuse_last + (size_t)b * CC * DD;
    for (int c = w; c < CC; c += 4) {
        const float* fr = fb + (size_t)c * DD + lane * 8;
        float4 a0 = *(const float4*)fr;
        float4 a1 = *(const float4*)(fr + 4);
        float ss = a0.x * a0.x + a0.y * a0.y + a0.z * a0.z + a0.w * a0.w +
                   a1.x * a1.x + a1.y * a1.y + a1.z * a1.z + a1.w * a1.w;
#pragma unroll
        for (int off = 32; off > 0; off >>= 1) ss += __shfl_xor(ss, off);
        if (lane == 0) invn[c] = 1.0f / fmaxf(sqrtf(ss), 1e-12f);
    }
    __syncthreads();
    for (int g = w; g < CC; g += 4) {
        int k = g / 6;
        const float* ar = ce + (size_t)g * DD + lane * 8;
        float4 c0 = *(const float4*)ar;
        float4 c1 = *(const float4*)(ar + 4);
        float av[8] = {c0.x, c0.y, c0.z, c0.w, c1.x, c1.y, c1.z, c1.w};
        float accp = 0.0f;
        for (int p = 0; p < 6; ++p) {
            int row = k * 6 + p;
            const float* fr = fb + (size_t)row * DD + lane * 8;
            float4 f0 = *(const float4*)fr;
            float4 f1 = *(const float4*)(fr + 4);
            float fv[8] = {f0.x, f0.y, f0.z, f0.w, f1.x, f1.y, f1.z, f1.w};
            float d = 0.0f;
#pragma unroll
            for (int j = 0; j < 8; ++j) d += fv[j] * av[j];
            accp += d * invn[row];
        }
#pragma unroll
        for (int off = 32; off > 0; off >>= 1) accp += __shfl_xor(accp, off);
        if (lane == 0) img[g] = accp * (100.0f / 6.0f);
    }
    __syncthreads();
    if (t < CC) out[BB * 7 + b * CC + t] = img[t];
    if (t < 7) {
        float sacc = b_cls[t];
        for (int c = 0; c < CC; ++c) sacc += img[c] * W_cls[t * CC + c];
        out[b * 7 + t] = sacc;
    }
    if (b == 0 && t == 0) out[BB * 7 + BB * CC] = loss_acc[0] * (1.0f / LOSS_DEN);
}

// ---------------------------------------------------------------------------
extern "C" void kernel_launch(void* const* d_in, const int* in_sizes, int n_in,
                              void* d_out, int out_size, void* d_ws, size_t ws_size,
                              hipStream_t stream) {
    const float* feats = (const float*)d_in[0];
    const float* ce = (const float*)d_in[1];
    const float* W_lin = (const float*)d_in[2];
    const float* b_lin = (const float*)d_in[3];
    const float* W_proj = (const float*)d_in[4];
    const float* W_gate = (const float*)d_in[5];
    const float* b_gate = (const float*)d_in[6];
    const float* W_upd = (const float*)d_in[7];
    const float* b_upd = (const float*)d_in[8];
    const float* W_cls = (const float*)d_in[9];
    const float* b_cls = (const float*)d_in[10];
    float* out = (float*)d_out;

    char* base = (char*)d_ws;
    size_t off = 0;
    auto alloc = [&](size_t bytes) -> char* {
        char* r = base + off;
        off += (bytes + 255) & ~(size_t)255;
        return r;
    };
    float* vt = (float*)alloc((size_t)LL * BB * VV * DD * 4);
    float* ctx = (float*)alloc((size_t)LL * BB * DD * 4);
    float* qbuf[2] = {(float*)alloc((size_t)BB * CC * DD * 4), (float*)alloc((size_t)BB * CC * DD * 4)};
    float* fbuf[2] = {(float*)alloc((size_t)BB * CC * DD * 4), (float*)alloc((size_t)BB * CC * DD * 4)};
    float* loss = (float*)alloc(256);
    u16* Xh = (u16*)alloc((size_t)LL * BB * VV * DV * 2);
    u16* Xl = (u16*)alloc((size_t)LL * BB * VV * DV * 2);
    u16* Wlh = (u16*)alloc((size_t)DD * DV * 2);
    u16* Wll = (u16*)alloc((size_t)DD * DV * 2);
    u16* Wgh = (u16*)alloc((size_t)DD * 1536 * 2);
    u16* Wgl = (u16*)alloc((size_t)DD * 1536 * 2);
    u16* Wuh = (u16*)alloc((size_t)DD * 1024 * 2);
    u16* Wul = (u16*)alloc((size_t)DD * 1024 * 2);
    u16* ch = (u16*)alloc((size_t)LL * BB * DD * 2);
    u16* cl = (u16*)alloc((size_t)LL * BB * DD * 2);
    u16* fh = (u16*)alloc((size_t)BB * CC * DD * 2);
    u16* fl = (u16*)alloc((size_t)BB * CC * DD * 2);
    u16* qph[2] = {(u16*)alloc((size_t)BB * CC * DD * 2), (u16*)alloc((size_t)BB * CC * DD * 2)};
    u16* qpl[2] = {(u16*)alloc((size_t)BB * CC * DD * 2), (u16*)alloc((size_t)BB * CC * DD * 2)};

    // Layer-independent precompute
    pool_split<<<LL * BB * VV, 256, 0, stream>>>(feats, Xh, Xl);
    split_kernel<<<(DD * DV + 255) / 256, 256, 0, stream>>>(W_lin, Wlh, Wll, DD * DV);
    split_kernel<<<(DD * 1536 + 255) / 256, 256, 0, stream>>>(W_gate, Wgh, Wgl, DD * 1536);
    split_kernel<<<(DD * 1024 + 255) / 256, 256, 0, stream>>>(W_upd, Wuh, Wul, DD * 1024);
    {
        dim3 g(LL * BB / 64, DD / 64);
        gemm_nt<<<g, 256, 0, stream>>>(feats, SS * DV, W_proj, DV, nullptr, ctx);
    }
    split_kernel<<<(LL * BB * DD + 255) / 256, 256, 0, stream>>>(ctx, ch, cl, LL * BB * DD);
    init_q_kernel<<<(BB * CC * DD) / 256, 256, 0, stream>>>(ce, qbuf[0], qph[0], qpl[0]);
    zero1_kernel<<<1, 1, 0, stream>>>(loss);
    {
        dim3 g(147, 8);  // M=18816/128, N=512/64
        vt_gemm<<<g, 256, 0, stream>>>(Xh, Xl, Wlh, Wll, b_lin, vt);
    }

    int qc = 0;
    for (int l = 0; l < LL; ++l) {
        float* fcur = fbuf[l & 1];
        float* fprev = fbuf[(l & 1) ^ 1];
        attn_fuse<<<BB * CC, 64, 0, stream>>>(qbuf[qc], vt + (size_t)l * BB * VV * DD, fprev,
                                              fcur, fh, fl, loss, l > 0 ? 1 : 0);
        if (l < LL - 1) {
            dim3 g(BB * CC / 64, DD / 64);
            gate_upd_mfma<<<g, 256, 0, stream>>>(fh, fl, qph[qc], qpl[qc],
                                                 ch + (size_t)l * BB * DD, cl + (size_t)l * BB * DD,
                                                 Wgh, Wgl, Wuh, Wul, b_gate, b_upd,
                                                 qbuf[qc], qbuf[qc ^ 1], qph[qc ^ 1], qpl[qc ^ 1]);
            qc ^= 1;
        }
    }

    final_kernel<<<BB, 256, 0, stream>>>(fbuf[(LL - 1) & 1], ce, W_cls, b_cls, loss, out);
}